// Round 5
// baseline (1796.250 us; speedup 1.0000x reference)
//
#include <hip/hip_runtime.h>
#include <hip/hip_bf16.h>
#include <cstddef>

#define N_NODES 16000
#define N_EDGES 256000
#define DIM 256
#define HEADS 8
#define DFF 1024
#define LN_EPS 1e-5f
#define CNT ((float)((size_t)N_NODES * DIM))
#define RSDH 0.17677669529663687f

typedef __attribute__((ext_vector_type(8))) short short8;
typedef __attribute__((ext_vector_type(4))) float floatx4;

__device__ __forceinline__ float bf2f(unsigned int s) {
    return __uint_as_float(s << 16);
}

__device__ __forceinline__ float2 ln_ms(const float* __restrict__ s) {
    float mu = s[0] * (1.0f / CNT);
    float var = s[1] * (1.0f / CNT) - mu * mu;
    float2 r; r.x = mu; r.y = 1.0f / (sqrtf(fmaxf(var, 0.0f)) + LN_EPS);
    return r;
}

// async global->LDS, 16B per lane (global_load_lds_dwordx4)
__device__ __forceinline__ void async16(const __hip_bfloat16* g, __hip_bfloat16* l) {
    __builtin_amdgcn_global_load_lds(
        (const __attribute__((address_space(1))) void*)g,
        (__attribute__((address_space(3))) void*)l, 16, 0, 0);
}

__device__ __forceinline__ void pack8(__hip_bfloat16* d, float4 a, float4 b) {
    union { short8 f; __hip_bfloat16 h[8]; } u;
    u.h[0] = __float2bfloat16(a.x); u.h[1] = __float2bfloat16(a.y);
    u.h[2] = __float2bfloat16(a.z); u.h[3] = __float2bfloat16(a.w);
    u.h[4] = __float2bfloat16(b.x); u.h[5] = __float2bfloat16(b.y);
    u.h[6] = __float2bfloat16(b.z); u.h[7] = __float2bfloat16(b.w);
    *(short8*)d = u.f;
}

__device__ __forceinline__ float4 lnaff(float4 v, float4 g, float4 b, float mu, float sc) {
    v.x = (v.x - mu) * sc * g.x + b.x;
    v.y = (v.y - mu) * sc * g.y + b.y;
    v.z = (v.z - mu) * sc * g.z + b.z;
    v.w = (v.w - mu) * sc * g.w + b.w;
    return v;
}

// ---------------- bf16 MFMA GEMM: C[M,N] = A[M,K] @ Bt[N,K]^T ----------------
// TM=128: 128x128 tile, 4 waves x (4x4) frags. TM=64: 64x128, 4 waves x (4x2).
// ACVT: A fp32, converted during staging (optional LN affine on read, lnA_*).
// RES:  residual read (optional LN affine on read, lnR_*).
// OBF16: 0 = fp32 out, 1 = bf16 out,
//        3 = dual: cols<512 -> fp32 to C (stride 512); cols>=512 -> bf16
//            K|V 4-chunk interleave to C2 (stride 512). Branch uniform/block.
// ostats: if non-null, block-reduced sum/sumsq of outputs -> atomicAdd.
template<int BIAS, int RELU, int RES, int OBF16, int ACVT, int TM>
__global__ __launch_bounds__(256) void mgemm_k(
    const void* __restrict__ Ap, const __hip_bfloat16* __restrict__ Bt,
    const float* __restrict__ bias, const float* __restrict__ res,
    void* __restrict__ C, void* __restrict__ C2, int M, int K, int N,
    const float* __restrict__ lnA_s, const float* __restrict__ lnA_g,
    const float* __restrict__ lnA_b,
    const float* __restrict__ lnR_s, const float* __restrict__ lnR_g,
    const float* __restrict__ lnR_b,
    float* __restrict__ ostats)
{
    __shared__ __hip_bfloat16 As[TM * 32];    // [m][k] row-major
    __shared__ __hip_bfloat16 Bs[128 * 32];   // [n][k] row-major, 8 KB
    __shared__ float rs[8];
    const int tid = threadIdx.x;
    const int lane = tid & 63, wv = tid >> 6;
    const int wm = (TM == 128) ? (wv & 1) * 64 : 0;
    const int wn = (TM == 128) ? (wv >> 1) * 64 : wv * 32;
    const int NJ = (TM == 128) ? 4 : 2;       // column frags per wave
    const int row0 = blockIdx.y * TM, col0 = blockIdx.x * 128;
    const int lr = tid >> 2;            // 0..63: tile row
    const int lk = (tid & 3) * 8;       // k offset 0/8/16/24

    float muA = 0.0f, scA = 1.0f;
    if (ACVT && lnA_s) { float2 t = ln_ms(lnA_s); muA = t.x; scA = t.y; }

    floatx4 acc[4][4];
    const floatx4 zf = {0.f, 0.f, 0.f, 0.f};
    #pragma unroll
    for (int i = 0; i < 4; i++)
        #pragma unroll
        for (int j = 0; j < 4; j++) acc[i][j] = zf;

    const int a_fo = (wm + (lane & 15)) * 32 + (lane >> 4) * 8;
    const int b_fo = (wn + (lane & 15)) * 32 + (lane >> 4) * 8;

    for (int k0 = 0; k0 < K; k0 += 32) {
        if (ACVT) {
            const float* A = (const float*)Ap;
            const float* p0 = A + (size_t)(row0 + lr) * K + k0 + lk;
            float4 v0 = *(const float4*)(p0);
            float4 v1 = *(const float4*)(p0 + 4);
            if (lnA_s) {
                float4 ga = *(const float4*)(lnA_g + k0 + lk);
                float4 gb = *(const float4*)(lnA_g + k0 + lk + 4);
                float4 ba = *(const float4*)(lnA_b + k0 + lk);
                float4 bb = *(const float4*)(lnA_b + k0 + lk + 4);
                v0 = lnaff(v0, ga, ba, muA, scA);
                v1 = lnaff(v1, gb, bb, muA, scA);
                if (TM == 128) {
                    const float* p1 = A + (size_t)(row0 + lr + 64) * K + k0 + lk;
                    float4 w0 = lnaff(*(const float4*)(p1), ga, ba, muA, scA);
                    float4 w1 = lnaff(*(const float4*)(p1 + 4), gb, bb, muA, scA);
                    pack8(As + 2048 + tid * 8, w0, w1);
                }
            } else if (TM == 128) {
                const float* p1 = A + (size_t)(row0 + lr + 64) * K + k0 + lk;
                pack8(As + 2048 + tid * 8, *(const float4*)(p1), *(const float4*)(p1 + 4));
            }
            pack8(As + tid * 8, v0, v1);
        } else {
            const __hip_bfloat16* A = (const __hip_bfloat16*)Ap;
            async16(A + (size_t)(row0 + lr) * K + k0 + lk, As + tid * 8);
            if (TM == 128)
                async16(A + (size_t)(row0 + lr + 64) * K + k0 + lk, As + 2048 + tid * 8);
        }
        async16(Bt + (size_t)(col0 + lr) * K + k0 + lk, Bs + tid * 8);
        async16(Bt + (size_t)(col0 + lr + 64) * K + k0 + lk, Bs + 2048 + tid * 8);
        __syncthreads();
        short8 a[4], b[4];
        #pragma unroll
        for (int i = 0; i < 4; i++)
            a[i] = *(const short8*)(As + a_fo + i * 16 * 32);
        #pragma unroll
        for (int j = 0; j < NJ; j++)
            b[j] = *(const short8*)(Bs + b_fo + j * 16 * 32);
        #pragma unroll
        for (int i = 0; i < 4; i++)
            #pragma unroll
            for (int j = 0; j < NJ; j++)
                acc[i][j] = __builtin_amdgcn_mfma_f32_16x16x32_bf16(a[i], b[j], acc[i][j], 0, 0, 0);
        __syncthreads();
    }
    // epilogue: D[m=(lane>>4)*4+r][n=lane&15] per 16x16 tile
    float muR = 0.0f, scR = 1.0f;
    if (RES && lnR_s) { float2 t = ln_ms(lnR_s); muR = t.x; scR = t.y; }
    const int rbase = row0 + wm + (lane >> 4) * 4;
    const int cbase = col0 + wn + (lane & 15);
    float s1 = 0.0f, s2 = 0.0f;
    #pragma unroll
    for (int j = 0; j < NJ; j++) {
        const int c = cbase + j * 16;
        float bb = BIAS ? bias[c] : 0.0f;
        float gr = (RES && lnR_s) ? lnR_g[c] : 1.0f;
        float br = (RES && lnR_s) ? lnR_b[c] : 0.0f;
        #pragma unroll
        for (int i = 0; i < 4; i++) {
            #pragma unroll
            for (int r = 0; r < 4; r++) {
                const int rr = rbase + i * 16 + r;
                float v = acc[i][j][r] + bb;
                if (RELU) v = fmaxf(v, 0.0f);
                if (RES) {
                    float rv = res[(size_t)rr * N + c];
                    if (lnR_s) rv = (rv - muR) * scR * gr + br;
                    v += rv;
                }
                if (ostats) { s1 += v; s2 += v * v; }
                if (OBF16 == 3) {
                    if (c < 512) {
                        ((float*)C)[(size_t)rr * 512 + c] = v;
                    } else {
                        const int cc = c - 512;
                        const int ccc = cc & 255;
                        const int idx = ((ccc >> 2) << 3) + (ccc & 3) + ((cc >> 8) << 2);
                        ((__hip_bfloat16*)C2)[(size_t)rr * 512 + idx] = __float2bfloat16(v);
                    }
                } else if (OBF16 == 1) {
                    ((__hip_bfloat16*)C)[(size_t)rr * N + c] = __float2bfloat16(v);
                } else {
                    ((float*)C)[(size_t)rr * N + c] = v;
                }
            }
        }
    }
    if (ostats) {
        #pragma unroll
        for (int o = 32; o > 0; o >>= 1) {
            s1 += __shfl_down(s1, o);
            s2 += __shfl_down(s2, o);
        }
        if (lane == 0) { rs[wv] = s1; rs[4 + wv] = s2; }
        __syncthreads();
        if (tid == 0) {
            atomicAdd(&ostats[0], rs[0] + rs[1] + rs[2] + rs[3]);
            atomicAdd(&ostats[1], rs[4] + rs[5] + rs[6] + rs[7]);
        }
    }
}

// ---------------- weight transpose + bf16 convert: dst[C][R] = src[R][C] -------
// batched over blockIdx.z with independent src/dst strides
__global__ __launch_bounds__(256) void tcvt_k(const float* __restrict__ src,
                                              __hip_bfloat16* __restrict__ dst,
                                              int R, int C, int sStride, int dStride)
{
    src += (size_t)blockIdx.z * sStride;
    dst += (size_t)blockIdx.z * dStride;
    __shared__ float t[32][33];
    const int c0 = blockIdx.x * 32, r0 = blockIdx.y * 32;
    const int tx = threadIdx.x & 31, ty = threadIdx.x >> 5;   // 32 x 8
    #pragma unroll
    for (int j = 0; j < 32; j += 8)
        t[ty + j][tx] = src[(size_t)(r0 + ty + j) * C + c0 + tx];
    __syncthreads();
    #pragma unroll
    for (int j = 0; j < 32; j += 8)
        dst[(size_t)(c0 + ty + j) * R + r0 + tx] = __float2bfloat16(t[tx][ty + j]);
}

// concat 4x256 biases -> [a|b|c|d] per transformer block (blockIdx.y)
__global__ __launch_bounds__(256) void bcat_k(const float* __restrict__ ba,
                                              const float* __restrict__ bb,
                                              const float* __restrict__ bc,
                                              const float* __restrict__ bd,
                                              float* __restrict__ o)
{
    const int z = blockIdx.y;
    int t = blockIdx.x * 256 + threadIdx.x;   // 1024
    float v = (t < 256) ? ba[z * 256 + t] : (t < 512) ? bb[z * 256 + t - 256]
            : (t < 768) ? bc[z * 256 + t - 512] : bd[z * 256 + t - 768];
    o[(size_t)z * 1024 + t] = v;
}

// ---------------- CSR build ----------------
__global__ __launch_bounds__(256) void hist_k(const int* __restrict__ dst, int* __restrict__ deg)
{
    int e = blockIdx.x * blockDim.x + threadIdx.x;
    if (e < N_EDGES) atomicAdd(&deg[dst[e]], 1);
}

__global__ __launch_bounds__(1024) void scan_k(const int* __restrict__ deg,
                                               int* __restrict__ rowptr,
                                               int* __restrict__ cursor)
{
    __shared__ int wsum[16];
    const int t = threadIdx.x;          // 16000 = 1000 threads x 16
    const int base = t * 16;
    int local[16];
    int s = 0;
    if (t < 1000) {
        #pragma unroll
        for (int j = 0; j < 16; j++) { local[j] = s; s += deg[base + j]; }
    }
    const int lane = t & 63, w = t >> 6;
    int v = s;
    #pragma unroll
    for (int off = 1; off < 64; off <<= 1) {
        int u = __shfl_up(v, off);
        if (lane >= off) v += u;
    }
    if (lane == 63) wsum[w] = v;
    __syncthreads();
    if (t == 0) {
        int r = 0;
        #pragma unroll
        for (int i = 0; i < 16; i++) { int u = wsum[i]; wsum[i] = r; r += u; }
    }
    __syncthreads();
    const int excl = v - s + wsum[w];
    if (t < 1000) {
        #pragma unroll
        for (int j = 0; j < 16; j++) {
            rowptr[base + j] = excl + local[j];
            cursor[base + j] = excl + local[j];
        }
        if (t == 999) rowptr[16000] = excl + s;
    }
}

// scatter: also emit src and logit scale in CSR-permuted order
__global__ __launch_bounds__(256) void scatter_k(const int* __restrict__ dst,
                                                 const int* __restrict__ src,
                                                 const float* __restrict__ xd,
                                                 int* __restrict__ cursor,
                                                 int* __restrict__ eperm,
                                                 int* __restrict__ srcp,
                                                 float* __restrict__ scale)
{
    int e = blockIdx.x * blockDim.x + threadIdx.x;
    if (e < N_EDGES) {
        int pos = atomicAdd(&cursor[dst[e]], 1);
        eperm[pos] = e;
        srcp[pos] = src[e];
        scale[pos] = RSDH / xd[e];
    }
}

// gather x_edge rows into CSR order, bf16 (once per launch)
__global__ __launch_bounds__(256) void eprep_k(const float* __restrict__ xe,
                                               const int* __restrict__ eperm,
                                               __hip_bfloat16* __restrict__ xeb)
{
    const int r = blockIdx.x * 4 + (threadIdx.x >> 6);
    const int lane = threadIdx.x & 63;
    const int e = eperm[r];
    float4 v = *(const float4*)(xe + (size_t)e * DIM + lane * 4);
    union { short4 s; __hip_bfloat16 h[4]; } u;
    u.h[0] = __float2bfloat16(v.x); u.h[1] = __float2bfloat16(v.y);
    u.h[2] = __float2bfloat16(v.z); u.h[3] = __float2bfloat16(v.w);
    *(short4*)(xeb + (size_t)r * DIM + lane * 4) = u.s;
}

// ---------------- per-node attention aggregation (TWO waves per dst node) ------
// node_agg is latency-bound (VALUBusy ~11%, HBM ~28%): the serial per-wave
// chain of ~deg dependent gather->dot->exp iterations is the critical path.
// Split each node's edge range across 2 waves (contiguous halves), each
// running the proven 2-wide-ILP pipeline; partials combined through LDS.
// kvb: bf16 K|V 4-chunk interleave -> one 16B load per lane per edge.
// Fused: x-residual (optional LN-on-read) + skip + LN1 stats.
__global__ __launch_bounds__(256) void node_agg_k(
    const float* __restrict__ qs, const __hip_bfloat16* __restrict__ kvb,
    const __hip_bfloat16* __restrict__ Ep,
    const int* __restrict__ srcp, const float* __restrict__ scale,
    const int* __restrict__ rowptr,
    const float* __restrict__ xsrc, const float* __restrict__ lnx_s,
    const float* __restrict__ lnx_g, const float* __restrict__ lnx_b,
    float* __restrict__ y, float* __restrict__ ostats)
{
    __shared__ float comb[2][64][5];
    __shared__ float rs[4];
    const int tid = threadIdx.x;
    const int lane = tid & 63;
    const int wv = tid >> 6;                    // 4 waves: 2 nodes x 2 parts
    const int ni = wv >> 1, part = wv & 1;
    const int n = blockIdx.x * 2 + ni;          // grid = N_NODES/2 exactly
    const float4 q = *(const float4*)(qs + (size_t)n * 512 + lane * 4);
    float aA0 = 0, aA1 = 0, aA2 = 0, aA3 = 0, denA = 0;
    float aB0 = 0, aB1 = 0, aB2 = 0, aB3 = 0, denB = 0;
    const int begF = rowptr[n], endF = rowptr[n + 1];
    const int mid = begF + ((endF - begF + 1) >> 1);
    const int beg = part ? mid : begF;
    const int end = part ? endF : mid;
    int i = beg;
    // slots A/B hold edges i, i+1; srcp prefetched one pair further ahead
    int sC = (i + 2 < end) ? srcp[i + 2] : 0;
    int sD = (i + 3 < end) ? srcp[i + 3] : 0;
    uint4 kvA = {0, 0, 0, 0}, kvB = {0, 0, 0, 0};
    uint2 ebA = {0, 0}, ebB = {0, 0};
    float scA = 0.f, scB = 0.f;
    if (i < end) {
        const int sA = srcp[i];
        kvA = *(const uint4*)(kvb + (size_t)sA * 512 + lane * 8);
        ebA = *(const uint2*)(Ep + (size_t)i * DIM + lane * 4);
        scA = scale[i];
    }
    if (i + 1 < end) {
        const int sB = srcp[i + 1];
        kvB = *(const uint4*)(kvb + (size_t)sB * 512 + lane * 8);
        ebB = *(const uint2*)(Ep + (size_t)(i + 1) * DIM + lane * 4);
        scB = scale[i + 1];
    }
    while (i + 1 < end) {
        const uint4 kA = kvA, kB = kvB;
        const uint2 eA = ebA, eB = ebB;
        const float cA = scA, cB = scB;
        if (i + 2 < end) {
            kvA = *(const uint4*)(kvb + (size_t)sC * 512 + lane * 8);
            ebA = *(const uint2*)(Ep + (size_t)(i + 2) * DIM + lane * 4);
            scA = scale[i + 2];
            sC = (i + 4 < end) ? srcp[i + 4] : 0;
        }
        if (i + 3 < end) {
            kvB = *(const uint4*)(kvb + (size_t)sD * 512 + lane * 8);
            ebB = *(const uint2*)(Ep + (size_t)(i + 3) * DIM + lane * 4);
            scB = scale[i + 3];
            sD = (i + 5 < end) ? srcp[i + 5] : 0;
        }
        const float eA0 = bf2f(eA.x & 0xffffu), eA1 = bf2f(eA.x >> 16);
        const float eA2 = bf2f(eA.y & 0xffffu), eA3 = bf2f(eA.y >> 16);
        const float eB0 = bf2f(eB.x & 0xffffu), eB1 = bf2f(eB.x >> 16);
        const float eB2 = bf2f(eB.y & 0xffffu), eB3 = bf2f(eB.y >> 16);
        float pA = q.x * (bf2f(kA.x & 0xffffu) + eA0)
                 + q.y * (bf2f(kA.x >> 16) + eA1)
                 + q.z * (bf2f(kA.y & 0xffffu) + eA2)
                 + q.w * (bf2f(kA.y >> 16) + eA3);
        float pB = q.x * (bf2f(kB.x & 0xffffu) + eB0)
                 + q.y * (bf2f(kB.x >> 16) + eB1)
                 + q.z * (bf2f(kB.y & 0xffffu) + eB2)
                 + q.w * (bf2f(kB.y >> 16) + eB3);
        pA += __shfl_xor(pA, 1); pB += __shfl_xor(pB, 1);
        pA += __shfl_xor(pA, 2); pB += __shfl_xor(pB, 2);
        pA += __shfl_xor(pA, 4); pB += __shfl_xor(pB, 4);
        const float exA = __expf(pA * cA);
        const float exB = __expf(pB * cB);
        denA += exA; denB += exB;
        aA0 = fmaf(bf2f(kA.z & 0xffffu) + eA0, exA, aA0);
        aA1 = fmaf(bf2f(kA.z >> 16) + eA1, exA, aA1);
        aA2 = fmaf(bf2f(kA.w & 0xffffu) + eA2, exA, aA2);
        aA3 = fmaf(bf2f(kA.w >> 16) + eA3, exA, aA3);
        aB0 = fmaf(bf2f(kB.z & 0xffffu) + eB0, exB, aB0);
        aB1 = fmaf(bf2f(kB.z >> 16) + eB1, exB, aB1);
        aB2 = fmaf(bf2f(kB.w & 0xffffu) + eB2, exB, aB2);
        aB3 = fmaf(bf2f(kB.w >> 16) + eB3, exB, aB3);
        i += 2;
    }
    if (i < end) {    // odd tail: edge i sits in the A slot
        const float e0 = bf2f(ebA.x & 0xffffu), e1 = bf2f(ebA.x >> 16);
        const float e2 = bf2f(ebA.y & 0xffffu), e3 = bf2f(ebA.y >> 16);
        float pA = q.x * (bf2f(kvA.x & 0xffffu) + e0)
                 + q.y * (bf2f(kvA.x >> 16) + e1)
                 + q.z * (bf2f(kvA.y & 0xffffu) + e2)
                 + q.w * (bf2f(kvA.y >> 16) + e3);
        pA += __shfl_xor(pA, 1);
        pA += __shfl_xor(pA, 2);
        pA += __shfl_xor(pA, 4);
        const float ex = __expf(pA * scA);
        denA += ex;
        aA0 = fmaf(bf2f(kvA.z & 0xffffu) + e0, ex, aA0);
        aA1 = fmaf(bf2f(kvA.z >> 16) + e1, ex, aA1);
        aA2 = fmaf(bf2f(kvA.w & 0xffffu) + e2, ex, aA2);
        aA3 = fmaf(bf2f(kvA.w >> 16) + e3, ex, aA3);
    }
    float den = denA + denB;
    float a0 = aA0 + aB0, a1 = aA1 + aB1, a2 = aA2 + aB2, a3 = aA3 + aB3;
    // combine the two waves of this node through LDS
    if (part) {
        comb[ni][lane][0] = den;
        comb[ni][lane][1] = a0; comb[ni][lane][2] = a1;
        comb[ni][lane][3] = a2; comb[ni][lane][4] = a3;
    }
    __syncthreads();
    if (!part) {
        den += comb[ni][lane][0];
        a0 += comb[ni][lane][1]; a1 += comb[ni][lane][2];
        a2 += comb[ni][lane][3]; a3 += comb[ni][lane][4];
        const float dn = 1.0f / (den + 1e-16f);
        const size_t o = (size_t)n * DIM + lane * 4;
        float4 xr = *(const float4*)(xsrc + o);
        if (lnx_s) {
            float2 t = ln_ms(lnx_s);
            const float4 g4 = *(const float4*)(lnx_g + lane * 4);
            const float4 b4 = *(const float4*)(lnx_b + lane * 4);
            xr = lnaff(xr, g4, b4, t.x, t.y);
        }
        const float4 sr = *(const float4*)(qs + (size_t)n * 512 + 256 + lane * 4);
        float4 out;
        out.x = xr.x + a0 * dn + sr.x;
        out.y = xr.y + a1 * dn + sr.y;
        out.z = xr.z + a2 * dn + sr.z;
        out.w = xr.w + a3 * dn + sr.w;
        *(float4*)(y + o) = out;
        // LN1 stats (partial, this wave)
        float s1 = out.x + out.y + out.z + out.w;
        float s2 = out.x * out.x + out.y * out.y + out.z * out.z + out.w * out.w;
        #pragma unroll
        for (int of = 32; of > 0; of >>= 1) {
            s1 += __shfl_down(s1, of);
            s2 += __shfl_down(s2, of);
        }
        if (lane == 0) { rs[ni] = s1; rs[2 + ni] = s2; }
    }
    __syncthreads();
    if (tid == 0) {
        atomicAdd(&ostats[0], rs[0] + rs[1]);
        atomicAdd(&ostats[1], rs[2] + rs[3]);
    }
}

// ---------------- final LN apply (only for d_out) ----------------
__global__ __launch_bounds__(256) void apply_k(
    const float* __restrict__ y, const float* __restrict__ stats,
    const float* __restrict__ g, const float* __restrict__ b,
    float* __restrict__ xo)
{
    int idx = blockIdx.x * blockDim.x + threadIdx.x;  // float4 index
    float2 t = ln_ms(stats);
    int cb = (idx & 63) * 4;
    float4 v  = *(const float4*)(y + (size_t)idx * 4);
    float4 gv = *(const float4*)(g + cb);
    float4 bv = *(const float4*)(b + cb);
    *(float4*)(xo + (size_t)idx * 4) = lnaff(v, gv, bv, t.x, t.y);
}

extern "C" void kernel_launch(void* const* d_in, const int* in_sizes, int n_in,
                              void* d_out, int out_size, void* d_ws, size_t ws_size,
                              hipStream_t stream) {
    const float* x_in   = (const float*)d_in[0];
    const int*   ei     = (const int*)d_in[1];
    const int*   src    = ei;                 // edge_index[0]
    const int*   dstp   = ei + N_EDGES;       // edge_index[1]
    const float* x_edge = (const float*)d_in[2];
    const float* x_dist = (const float*)d_in[3];
    const float* Wq  = (const float*)d_in[4];
    const float* bq  = (const float*)d_in[5];
    const float* Wk  = (const float*)d_in[6];
    const float* bk  = (const float*)d_in[7];
    const float* Wv  = (const float*)d_in[8];
    const float* bv  = (const float*)d_in[9];
    const float* We  = (const float*)d_in[10];
    const float* Wsk = (const float*)d_in[11];
    const float* bsk = (const float*)d_in[12];
    const float* g1  = (const float*)d_in[13];
    const float* b1  = (const float*)d_in[14];
    const float* W1  = (const float*)d_in[15];
    const float* c1  = (const float*)d_in[16];
    const float* W2  = (const float*)d_in[17];
    const float* c2  = (const float*)d_in[18];
    const float* g2  = (const float*)d_in[19];
    const float* b2  = (const float*)d_in[20];

    // ---- workspace carve ----
    char* p = (char*)d_ws;
    float* ybuf = (float*)p; p += (size_t)N_NODES * DIM * sizeof(float);           // 16.4 MB
    float* qsb  = (float*)p; p += (size_t)N_NODES * 512 * sizeof(float);           // 32.8 MB  [Q|S] fp32
    __hip_bfloat16* kvb = (__hip_bfloat16*)p; p += (size_t)N_NODES * 512 * 2;      // 16.4 MB  [K|V] bf16 interleaved
    __hip_bfloat16* hb16 = (__hip_bfloat16*)p; p += (size_t)N_NODES * 1024 * 2;    // 32.8 MB
    __hip_bfloat16* Ep   = (__hip_bfloat16*)p; p += (size_t)N_EDGES * DIM * 2;     // 131 MB
    __hip_bfloat16* xeb  = (__hip_bfloat16*)p; p += (size_t)N_EDGES * DIM * 2;     // 131 MB
    __hip_bfloat16* WqkvsT = (__hip_bfloat16*)p; p += (size_t)3 * 1024 * 256 * 2;  // [Wq|Wsk|Wk|Wv]^T
    __hip_bfloat16* WeT    = (__hip_bfloat16*)p; p += (size_t)3 * 256 * 256 * 2;
    __hip_bfloat16* W1T    = (__hip_bfloat16*)p; p += (size_t)3 * 1024 * 256 * 2;
    __hip_bfloat16* W2T    = (__hip_bfloat16*)p; p += (size_t)3 * 256 * 1024 * 2;
    float* bqkvs = (float*)p; p += (size_t)3 * 1024 * sizeof(float);               // [bq|bsk|bk|bv]
    float* stats = (float*)p;  p += 64;                       // [block][ln1_s,ln1_ss,ln2_s,ln2_ss]
    int* deg     = (int*)p;    p += (size_t)N_NODES * sizeof(int);
    int* rowptr  = (int*)p;    p += (size_t)(N_NODES + 4) * sizeof(int);
    int* cursor  = (int*)p;    p += (size_t)N_NODES * sizeof(int);
    int* eperm   = (int*)p;    p += (size_t)N_EDGES * sizeof(int);
    int* srcp    = (int*)p;    p += (size_t)N_EDGES * sizeof(int);
    float* scale = (float*)p;  p += (size_t)N_EDGES * sizeof(float);

    const dim3 blk(256);

    // ---- CSR build (edge list constant across blocks) ----
    hipMemsetAsync(deg, 0, (size_t)N_NODES * sizeof(int), stream);
    hipMemsetAsync(stats, 0, 48, stream);
    hist_k<<<N_EDGES / 256, blk, 0, stream>>>(dstp, deg);
    scan_k<<<1, 1024, 0, stream>>>(deg, rowptr, cursor);
    scatter_k<<<N_EDGES / 256, blk, 0, stream>>>(dstp, src, x_dist, cursor, eperm, srcp, scale);
    eprep_k<<<N_EDGES / 4, blk, 0, stream>>>(x_edge, eperm, xeb);

    // ---- weight prep: transpose + bf16 convert, order [Q|S|K|V], batched z=3 ----
    tcvt_k<<<dim3(8, 8, 3), blk, 0, stream>>>(Wq,  WqkvsT + 0 * 65536, 256, 256, 65536, 262144);
    tcvt_k<<<dim3(8, 8, 3), blk, 0, stream>>>(Wsk, WqkvsT + 1 * 65536, 256, 256, 65536, 262144);
    tcvt_k<<<dim3(8, 8, 3), blk, 0, stream>>>(Wk,  WqkvsT + 2 * 65536, 256, 256, 65536, 262144);
    tcvt_k<<<dim3(8, 8, 3), blk, 0, stream>>>(Wv,  WqkvsT + 3 * 65536, 256, 256, 65536, 262144);
    tcvt_k<<<dim3(8, 8, 3), blk, 0, stream>>>(We,  WeT, 256, 256, 65536, 65536);
    tcvt_k<<<dim3(32, 8, 3), blk, 0, stream>>>(W1, W1T, 256, 1024, 262144, 262144);
    tcvt_k<<<dim3(8, 32, 3), blk, 0, stream>>>(W2, W2T, 1024, 256, 262144, 262144);
    bcat_k<<<dim3(4, 3), blk, 0, stream>>>(bq, bsk, bk, bv, bqkvs);

    for (int i = 0; i < 3; i++) {
        const size_t bo = (size_t)i * DIM;
        const size_t b1o = (size_t)i * DFF;
        float* ln1 = stats + (size_t)i * 4;
        float* ln2 = stats + (size_t)i * 4 + 2;
        // LN2 of previous block, applied on-read to x
        const float* pls = (i == 0) ? nullptr : stats + (size_t)(i - 1) * 4 + 2;
        const float* plg = (i == 0) ? nullptr : g2 + (size_t)(i - 1) * 256;
        const float* plb = (i == 0) ? nullptr : b2 + (size_t)(i - 1) * 256;
        const float* xsrc = (i == 0) ? x_in : ybuf;

        // fused Q|S|K|V projection: LN(x) [16000,256] x [256,1024]
        // cols 0-511 -> qsb fp32; cols 512-1023 -> kvb bf16 interleaved
        mgemm_k<1,0,0,3,1,128><<<dim3(8, 125), blk, 0, stream>>>(
            xsrc, WqkvsT + (size_t)i * 262144, bqkvs + (size_t)i * 1024, nullptr,
            qsb, kvb, N_NODES, DIM, 1024, pls, plg, plb, nullptr, nullptr, nullptr, nullptr);
        // edge projection (CSR-ordered bf16 A): [256000,256] x [256,256] -> bf16
        mgemm_k<0,0,0,1,0,128><<<dim3(2, 2000), blk, 0, stream>>>(
            xeb, WeT + (size_t)i * 65536, nullptr, nullptr,
            Ep, nullptr, N_EDGES, DIM, DIM, nullptr, nullptr, nullptr, nullptr, nullptr, nullptr, nullptr);
        // attention aggregation + residual + skip + LN1 stats -> ybuf
        // 2 waves per node: halves the latency-bound serial edge chain
        node_agg_k<<<N_NODES / 2, blk, 0, stream>>>(qsb, kvb, Ep, srcp, scale, rowptr,
                                                    xsrc, pls, plg, plb, ybuf, ln1);
        // FFN1: LN1(y) x W1 + bias + relu -> bf16
        mgemm_k<1,1,0,1,1,128><<<dim3(8, 125), blk, 0, stream>>>(
            ybuf, W1T + (size_t)i * 262144, c1 + b1o, nullptr,
            hb16, nullptr, N_NODES, DIM, DFF, ln1, g1 + bo, b1 + bo, nullptr, nullptr, nullptr, nullptr);
        // FFN2: h x W2 + bias + LN1(y) residual -> ybuf (in-place) + LN2 stats
        // TM=64: grid (2,250)=500 blocks -> 2 blocks/CU
        mgemm_k<1,0,1,0,0,64><<<dim3(2, 250), blk, 0, stream>>>(
            hb16, W2T + (size_t)i * 262144, c2 + bo, ybuf,
            ybuf, nullptr, N_NODES, DFF, DIM, nullptr, nullptr, nullptr, ln1, g1 + bo, b1 + bo, ln2);
        if (i == 2)
            apply_k<<<(N_NODES * DIM) / 1024, blk, 0, stream>>>(
                ybuf, ln2, g2 + bo, b2 + bo, (float*)d_out);
    }
}

// Round 6
// 1410.940 us; speedup vs baseline: 1.2731x; 1.2731x over previous
//
#include <hip/hip_runtime.h>
#include <hip/hip_bf16.h>
#include <cstddef>

#define N_NODES 16000
#define N_EDGES 256000
#define DIM 256
#define HEADS 8
#define DFF 1024
#define LN_EPS 1e-5f
#define CNT ((float)((size_t)N_NODES * DIM))
#define RSDH 0.17677669529663687f

typedef __attribute__((ext_vector_type(8))) short short8;
typedef __attribute__((ext_vector_type(4))) float floatx4;

__device__ __forceinline__ float bf2f(unsigned int s) {
    return __uint_as_float(s << 16);
}

__device__ __forceinline__ float2 ln_ms(const float* __restrict__ s) {
    float mu = s[0] * (1.0f / CNT);
    float var = s[1] * (1.0f / CNT) - mu * mu;
    float2 r; r.x = mu; r.y = 1.0f / (sqrtf(fmaxf(var, 0.0f)) + LN_EPS);
    return r;
}

// async global->LDS, 16B per lane (global_load_lds_dwordx4)
__device__ __forceinline__ void async16(const __hip_bfloat16* g, __hip_bfloat16* l) {
    __builtin_amdgcn_global_load_lds(
        (const __attribute__((address_space(1))) void*)g,
        (__attribute__((address_space(3))) void*)l, 16, 0, 0);
}

__device__ __forceinline__ void pack8(__hip_bfloat16* d, float4 a, float4 b) {
    union { short8 f; __hip_bfloat16 h[8]; } u;
    u.h[0] = __float2bfloat16(a.x); u.h[1] = __float2bfloat16(a.y);
    u.h[2] = __float2bfloat16(a.z); u.h[3] = __float2bfloat16(a.w);
    u.h[4] = __float2bfloat16(b.x); u.h[5] = __float2bfloat16(b.y);
    u.h[6] = __float2bfloat16(b.z); u.h[7] = __float2bfloat16(b.w);
    *(short8*)d = u.f;
}

__device__ __forceinline__ float4 lnaff(float4 v, float4 g, float4 b, float mu, float sc) {
    v.x = (v.x - mu) * sc * g.x + b.x;
    v.y = (v.y - mu) * sc * g.y + b.y;
    v.z = (v.z - mu) * sc * g.z + b.z;
    v.w = (v.w - mu) * sc * g.w + b.w;
    return v;
}

// ---------------- bf16 MFMA GEMM body: C[M,N] = A[M,K] @ Bt[N,K]^T -------------
// Device-callable so independent GEMMs can share one dispatch (block-uniform
// branch on block id). TM=128: 4 waves x (4x4) frags. TM=64: 4 waves x (4x2).
// ACVT: A fp32, converted during staging (optional LN affine on read, lnA_*).
// RES:  residual read (optional LN affine on read, lnR_*).
// OBF16: 0 = fp32 out, 1 = bf16 out,
//        3 = dual: cols<512 -> fp32 to C (stride 512); cols>=512 -> bf16
//            K|V 4-chunk interleave to C2 (stride 512). Branch uniform/block.
// ostats: if non-null, block-reduced sum/sumsq of outputs -> atomicAdd.
template<int BIAS, int RELU, int RES, int OBF16, int ACVT, int TM>
__device__ __forceinline__ void mgemm_body(
    const void* __restrict__ Ap, const __hip_bfloat16* __restrict__ Bt,
    const float* __restrict__ bias, const float* __restrict__ res,
    void* __restrict__ C, void* __restrict__ C2, int M, int K, int N,
    const float* __restrict__ lnA_s, const float* __restrict__ lnA_g,
    const float* __restrict__ lnA_b,
    const float* __restrict__ lnR_s, const float* __restrict__ lnR_g,
    const float* __restrict__ lnR_b,
    float* __restrict__ ostats,
    __hip_bfloat16* As, __hip_bfloat16* Bs, float* rs,
    int bx, int by)
{
    const int tid = threadIdx.x;
    const int lane = tid & 63, wv = tid >> 6;
    const int wm = (TM == 128) ? (wv & 1) * 64 : 0;
    const int wn = (TM == 128) ? (wv >> 1) * 64 : wv * 32;
    const int NJ = (TM == 128) ? 4 : 2;       // column frags per wave
    const int row0 = by * TM, col0 = bx * 128;
    const int lr = tid >> 2;            // 0..63: tile row
    const int lk = (tid & 3) * 8;       // k offset 0/8/16/24

    float muA = 0.0f, scA = 1.0f;
    if (ACVT && lnA_s) { float2 t = ln_ms(lnA_s); muA = t.x; scA = t.y; }

    floatx4 acc[4][4];
    const floatx4 zf = {0.f, 0.f, 0.f, 0.f};
    #pragma unroll
    for (int i = 0; i < 4; i++)
        #pragma unroll
        for (int j = 0; j < 4; j++) acc[i][j] = zf;

    const int a_fo = (wm + (lane & 15)) * 32 + (lane >> 4) * 8;
    const int b_fo = (wn + (lane & 15)) * 32 + (lane >> 4) * 8;

    for (int k0 = 0; k0 < K; k0 += 32) {
        if (ACVT) {
            const float* A = (const float*)Ap;
            const float* p0 = A + (size_t)(row0 + lr) * K + k0 + lk;
            float4 v0 = *(const float4*)(p0);
            float4 v1 = *(const float4*)(p0 + 4);
            if (lnA_s) {
                float4 ga = *(const float4*)(lnA_g + k0 + lk);
                float4 gb = *(const float4*)(lnA_g + k0 + lk + 4);
                float4 ba = *(const float4*)(lnA_b + k0 + lk);
                float4 bb = *(const float4*)(lnA_b + k0 + lk + 4);
                v0 = lnaff(v0, ga, ba, muA, scA);
                v1 = lnaff(v1, gb, bb, muA, scA);
                if (TM == 128) {
                    const float* p1 = A + (size_t)(row0 + lr + 64) * K + k0 + lk;
                    float4 w0 = lnaff(*(const float4*)(p1), ga, ba, muA, scA);
                    float4 w1 = lnaff(*(const float4*)(p1 + 4), gb, bb, muA, scA);
                    pack8(As + 2048 + tid * 8, w0, w1);
                }
            } else if (TM == 128) {
                const float* p1 = A + (size_t)(row0 + lr + 64) * K + k0 + lk;
                pack8(As + 2048 + tid * 8, *(const float4*)(p1), *(const float4*)(p1 + 4));
            }
            pack8(As + tid * 8, v0, v1);
        } else {
            const __hip_bfloat16* A = (const __hip_bfloat16*)Ap;
            async16(A + (size_t)(row0 + lr) * K + k0 + lk, As + tid * 8);
            if (TM == 128)
                async16(A + (size_t)(row0 + lr + 64) * K + k0 + lk, As + 2048 + tid * 8);
        }
        async16(Bt + (size_t)(col0 + lr) * K + k0 + lk, Bs + tid * 8);
        async16(Bt + (size_t)(col0 + lr + 64) * K + k0 + lk, Bs + 2048 + tid * 8);
        __syncthreads();
        short8 a[4], b[4];
        #pragma unroll
        for (int i = 0; i < 4; i++)
            a[i] = *(const short8*)(As + a_fo + i * 16 * 32);
        #pragma unroll
        for (int j = 0; j < NJ; j++)
            b[j] = *(const short8*)(Bs + b_fo + j * 16 * 32);
        #pragma unroll
        for (int i = 0; i < 4; i++)
            #pragma unroll
            for (int j = 0; j < NJ; j++)
                acc[i][j] = __builtin_amdgcn_mfma_f32_16x16x32_bf16(a[i], b[j], acc[i][j], 0, 0, 0);
        __syncthreads();
    }
    // epilogue: D[m=(lane>>4)*4+r][n=lane&15] per 16x16 tile
    float muR = 0.0f, scR = 1.0f;
    if (RES && lnR_s) { float2 t = ln_ms(lnR_s); muR = t.x; scR = t.y; }
    const int rbase = row0 + wm + (lane >> 4) * 4;
    const int cbase = col0 + wn + (lane & 15);
    float s1 = 0.0f, s2 = 0.0f;
    #pragma unroll
    for (int j = 0; j < NJ; j++) {
        const int c = cbase + j * 16;
        float bb = BIAS ? bias[c] : 0.0f;
        float gr = (RES && lnR_s) ? lnR_g[c] : 1.0f;
        float br = (RES && lnR_s) ? lnR_b[c] : 0.0f;
        #pragma unroll
        for (int i = 0; i < 4; i++) {
            #pragma unroll
            for (int r = 0; r < 4; r++) {
                const int rr = rbase + i * 16 + r;
                float v = acc[i][j][r] + bb;
                if (RELU) v = fmaxf(v, 0.0f);
                if (RES) {
                    float rv = res[(size_t)rr * N + c];
                    if (lnR_s) rv = (rv - muR) * scR * gr + br;
                    v += rv;
                }
                if (ostats) { s1 += v; s2 += v * v; }
                if (OBF16 == 3) {
                    if (c < 512) {
                        ((float*)C)[(size_t)rr * 512 + c] = v;
                    } else {
                        const int cc = c - 512;
                        const int ccc = cc & 255;
                        const int idx = ((ccc >> 2) << 3) + (ccc & 3) + ((cc >> 8) << 2);
                        ((__hip_bfloat16*)C2)[(size_t)rr * 512 + idx] = __float2bfloat16(v);
                    }
                } else if (OBF16 == 1) {
                    ((__hip_bfloat16*)C)[(size_t)rr * N + c] = __float2bfloat16(v);
                } else {
                    ((float*)C)[(size_t)rr * N + c] = v;
                }
            }
        }
    }
    if (ostats) {
        #pragma unroll
        for (int o = 32; o > 0; o >>= 1) {
            s1 += __shfl_down(s1, o);
            s2 += __shfl_down(s2, o);
        }
        if (lane == 0) { rs[wv] = s1; rs[4 + wv] = s2; }
        __syncthreads();
        if (tid == 0) {
            atomicAdd(&ostats[0], rs[0] + rs[1] + rs[2] + rs[3]);
            atomicAdd(&ostats[1], rs[4] + rs[5] + rs[6] + rs[7]);
        }
    }
}

// standalone GEMM dispatch
template<int BIAS, int RELU, int RES, int OBF16, int ACVT, int TM>
__global__ __launch_bounds__(256) void mgemm_k(
    const void* __restrict__ Ap, const __hip_bfloat16* __restrict__ Bt,
    const float* __restrict__ bias, const float* __restrict__ res,
    void* __restrict__ C, void* __restrict__ C2, int M, int K, int N,
    const float* __restrict__ lnA_s, const float* __restrict__ lnA_g,
    const float* __restrict__ lnA_b,
    const float* __restrict__ lnR_s, const float* __restrict__ lnR_g,
    const float* __restrict__ lnR_b,
    float* __restrict__ ostats)
{
    __shared__ __hip_bfloat16 As[TM * 32];
    __shared__ __hip_bfloat16 Bs[128 * 32];
    __shared__ float rs[8];
    mgemm_body<BIAS, RELU, RES, OBF16, ACVT, TM>(
        Ap, Bt, bias, res, C, C2, M, K, N, lnA_s, lnA_g, lnA_b,
        lnR_s, lnR_g, lnR_b, ostats, As, Bs, rs, blockIdx.x, blockIdx.y);
}

// merged dispatch: edge projection (blocks 0..3999) + QSKV projection (4000..4999).
// The two GEMMs are independent; co-dispatching lets the 1000-block projection
// fill CUs alongside the HBM-streaming edge GEMM instead of serializing.
__global__ __launch_bounds__(256) void projedge_k(
    const float* __restrict__ xsrc, const __hip_bfloat16* __restrict__ WqsT,
    const float* __restrict__ bqs, float* __restrict__ qsb,
    __hip_bfloat16* __restrict__ kvb,
    const __hip_bfloat16* __restrict__ xeb, const __hip_bfloat16* __restrict__ WeT,
    __hip_bfloat16* __restrict__ Ep,
    const float* __restrict__ pls, const float* __restrict__ plg,
    const float* __restrict__ plb)
{
    __shared__ __hip_bfloat16 As[128 * 32];
    __shared__ __hip_bfloat16 Bs[128 * 32];
    __shared__ float rs[8];
    const int b = blockIdx.x;
    if (b < 4000) {
        // edge projection: [256000,256] x [256,256] -> bf16 Ep
        mgemm_body<0, 0, 0, 1, 0, 128>(
            xeb, WeT, nullptr, nullptr, Ep, nullptr, N_EDGES, DIM, DIM,
            nullptr, nullptr, nullptr, nullptr, nullptr, nullptr, nullptr,
            As, Bs, rs, b & 1, b >> 1);
    } else {
        // Q|S|K|V projection: LN(x) [16000,256] x [256,1024]
        // cols 0-511 -> qsb fp32; 512-1023 -> kvb bf16 K|V-interleaved
        const int pb = b - 4000;
        mgemm_body<1, 0, 0, 3, 1, 128>(
            xsrc, WqsT, bqs, nullptr, qsb, kvb, N_NODES, DIM, 1024,
            pls, plg, plb, nullptr, nullptr, nullptr, nullptr,
            As, Bs, rs, pb & 7, pb >> 3);
    }
}

// ---------------- weight transpose + bf16 convert: dst[C][R] = src[R][C] -------
// batched over blockIdx.z with independent src/dst strides
__global__ __launch_bounds__(256) void tcvt_k(const float* __restrict__ src,
                                              __hip_bfloat16* __restrict__ dst,
                                              int R, int C, int sStride, int dStride)
{
    src += (size_t)blockIdx.z * sStride;
    dst += (size_t)blockIdx.z * dStride;
    __shared__ float t[32][33];
    const int c0 = blockIdx.x * 32, r0 = blockIdx.y * 32;
    const int tx = threadIdx.x & 31, ty = threadIdx.x >> 5;   // 32 x 8
    #pragma unroll
    for (int j = 0; j < 32; j += 8)
        t[ty + j][tx] = src[(size_t)(r0 + ty + j) * C + c0 + tx];
    __syncthreads();
    #pragma unroll
    for (int j = 0; j < 32; j += 8)
        dst[(size_t)(c0 + ty + j) * R + r0 + tx] = __float2bfloat16(t[tx][ty + j]);
}

// all four 256x256 QSKV weights x 3 transformer blocks in one dispatch:
// z = tb*4 + w, w in {Q,S,K,V}
__global__ __launch_bounds__(256) void tcvt4_k(const float* __restrict__ s0,
                                               const float* __restrict__ s1,
                                               const float* __restrict__ s2,
                                               const float* __restrict__ s3,
                                               __hip_bfloat16* __restrict__ dst)
{
    const int w = blockIdx.z & 3, tb = blockIdx.z >> 2;
    const float* src = ((w == 0) ? s0 : (w == 1) ? s1 : (w == 2) ? s2 : s3)
                       + (size_t)tb * 65536;
    __hip_bfloat16* d = dst + (size_t)tb * 262144 + (size_t)w * 65536;
    __shared__ float t[32][33];
    const int c0 = blockIdx.x * 32, r0 = blockIdx.y * 32;
    const int tx = threadIdx.x & 31, ty = threadIdx.x >> 5;   // 32 x 8
    #pragma unroll
    for (int j = 0; j < 32; j += 8)
        t[ty + j][tx] = src[(size_t)(r0 + ty + j) * 256 + c0 + tx];
    __syncthreads();
    #pragma unroll
    for (int j = 0; j < 32; j += 8)
        d[(size_t)(c0 + ty + j) * 256 + r0 + tx] = __float2bfloat16(t[tx][ty + j]);
}

// concat 4x256 biases -> [a|b|c|d] per transformer block (blockIdx.y)
__global__ __launch_bounds__(256) void bcat_k(const float* __restrict__ ba,
                                              const float* __restrict__ bb,
                                              const float* __restrict__ bc,
                                              const float* __restrict__ bd,
                                              float* __restrict__ o)
{
    const int z = blockIdx.y;
    int t = blockIdx.x * 256 + threadIdx.x;   // 1024
    float v = (t < 256) ? ba[z * 256 + t] : (t < 512) ? bb[z * 256 + t - 256]
            : (t < 768) ? bc[z * 256 + t - 512] : bd[z * 256 + t - 768];
    o[(size_t)z * 1024 + t] = v;
}

// ---------------- CSR build ----------------
__global__ __launch_bounds__(256) void hist_k(const int* __restrict__ dst, int* __restrict__ deg)
{
    int e = blockIdx.x * blockDim.x + threadIdx.x;
    if (e < N_EDGES) atomicAdd(&deg[dst[e]], 1);
}

__global__ __launch_bounds__(1024) void scan_k(const int* __restrict__ deg,
                                               int* __restrict__ rowptr,
                                               int* __restrict__ cursor)
{
    __shared__ int wsum[16];
    const int t = threadIdx.x;          // 16000 = 1000 threads x 16
    const int base = t * 16;
    int local[16];
    int s = 0;
    if (t < 1000) {
        #pragma unroll
        for (int j = 0; j < 16; j++) { local[j] = s; s += deg[base + j]; }
    }
    const int lane = t & 63, w = t >> 6;
    int v = s;
    #pragma unroll
    for (int off = 1; off < 64; off <<= 1) {
        int u = __shfl_up(v, off);
        if (lane >= off) v += u;
    }
    if (lane == 63) wsum[w] = v;
    __syncthreads();
    if (t == 0) {
        int r = 0;
        #pragma unroll
        for (int i = 0; i < 16; i++) { int u = wsum[i]; wsum[i] = r; r += u; }
    }
    __syncthreads();
    const int excl = v - s + wsum[w];
    if (t < 1000) {
        #pragma unroll
        for (int j = 0; j < 16; j++) {
            rowptr[base + j] = excl + local[j];
            cursor[base + j] = excl + local[j];
        }
        if (t == 999) rowptr[16000] = excl + s;
    }
}

// scatter: also emit src and logit scale in CSR-permuted order
__global__ __launch_bounds__(256) void scatter_k(const int* __restrict__ dst,
                                                 const int* __restrict__ src,
                                                 const float* __restrict__ xd,
                                                 int* __restrict__ cursor,
                                                 int* __restrict__ eperm,
                                                 int* __restrict__ srcp,
                                                 float* __restrict__ scale)
{
    int e = blockIdx.x * blockDim.x + threadIdx.x;
    if (e < N_EDGES) {
        int pos = atomicAdd(&cursor[dst[e]], 1);
        eperm[pos] = e;
        srcp[pos] = src[e];
        scale[pos] = RSDH / xd[e];
    }
}

// gather x_edge rows into CSR order, bf16 (once per launch)
__global__ __launch_bounds__(256) void eprep_k(const float* __restrict__ xe,
                                               const int* __restrict__ eperm,
                                               __hip_bfloat16* __restrict__ xeb)
{
    const int r = blockIdx.x * 4 + (threadIdx.x >> 6);
    const int lane = threadIdx.x & 63;
    const int e = eperm[r];
    float4 v = *(const float4*)(xe + (size_t)e * DIM + lane * 4);
    union { short4 s; __hip_bfloat16 h[4]; } u;
    u.h[0] = __float2bfloat16(v.x); u.h[1] = __float2bfloat16(v.y);
    u.h[2] = __float2bfloat16(v.z); u.h[3] = __float2bfloat16(v.w);
    *(short4*)(xeb + (size_t)r * DIM + lane * 4) = u.s;
}

// ---------------- per-node attention aggregation (one wave per dst node) --------
// Best measured structure (round-3): 1 wave/node, 4-wide tail-free pipeline.
// [round-5 lesson: 2-waves/node split REGRESSED 126->224us - barrier couples
//  waves to the slowest; short per-wave loops can't cover cold-start latency.]
// Ep/srcp/scale are CSR-ordered sequential streams; kvb gather is bf16 K|V
// 4-chunk interleaved -> one 16B load per lane per edge. Edge count padded to
// x4 by clamping indices to the last edge, exp masked to 0 for phantom slots.
// Fused: x-residual (optional LN-on-read) + skip + LN1 stats.
__global__ __launch_bounds__(256) void node_agg_k(
    const float* __restrict__ qs, const __hip_bfloat16* __restrict__ kvb,
    const __hip_bfloat16* __restrict__ Ep,
    const int* __restrict__ srcp, const float* __restrict__ scale,
    const int* __restrict__ rowptr,
    const float* __restrict__ xsrc, const float* __restrict__ lnx_s,
    const float* __restrict__ lnx_g, const float* __restrict__ lnx_b,
    float* __restrict__ y, float* __restrict__ ostats)
{
    __shared__ float rs[8];
    const int lane = threadIdx.x & 63;
    const int wv = threadIdx.x >> 6;
    const int n = blockIdx.x * 4 + wv;          // grid = N_NODES/4 exactly
    const float4 q = *(const float4*)(qs + (size_t)n * 512 + lane * 4);
    float ax0[4], ax1[4], ax2[4], ax3[4], den[4];
    #pragma unroll
    for (int t = 0; t < 4; t++) { ax0[t] = 0; ax1[t] = 0; ax2[t] = 0; ax3[t] = 0; den[t] = 0; }
    const int beg = rowptr[n], end = rowptr[n + 1];
    if (beg < end) {
        const int last = end - 1;
        uint4 kv[4]; uint2 eb[4]; float sc[4]; int sn[4];
        #pragma unroll
        for (int t = 0; t < 4; t++) {
            const int idx = min(beg + t, last);
            const int s = srcp[idx];
            kv[t] = *(const uint4*)(kvb + (size_t)s * 512 + lane * 8);
            eb[t] = *(const uint2*)(Ep + (size_t)idx * DIM + lane * 4);
            sc[t] = scale[idx];
        }
        #pragma unroll
        for (int t = 0; t < 4; t++)
            sn[t] = srcp[min(beg + 4 + t, last)];
        for (int i = beg; i < end; i += 4) {
            uint4 ckv[4]; uint2 ceb[4]; float csc[4];
            #pragma unroll
            for (int t = 0; t < 4; t++) { ckv[t] = kv[t]; ceb[t] = eb[t]; csc[t] = sc[t]; }
            if (i + 4 < end) {
                #pragma unroll
                for (int t = 0; t < 4; t++) {
                    const int idx = min(i + 4 + t, last);
                    kv[t] = *(const uint4*)(kvb + (size_t)sn[t] * 512 + lane * 8);
                    eb[t] = *(const uint2*)(Ep + (size_t)idx * DIM + lane * 4);
                    sc[t] = scale[idx];
                }
                #pragma unroll
                for (int t = 0; t < 4; t++)
                    sn[t] = srcp[min(i + 8 + t, last)];
            }
            float p[4];
            #pragma unroll
            for (int t = 0; t < 4; t++) {
                const float e0 = bf2f(ceb[t].x & 0xffffu), e1 = bf2f(ceb[t].x >> 16);
                const float e2 = bf2f(ceb[t].y & 0xffffu), e3 = bf2f(ceb[t].y >> 16);
                p[t] = q.x * (bf2f(ckv[t].x & 0xffffu) + e0)
                     + q.y * (bf2f(ckv[t].x >> 16) + e1)
                     + q.z * (bf2f(ckv[t].y & 0xffffu) + e2)
                     + q.w * (bf2f(ckv[t].y >> 16) + e3);
            }
            #pragma unroll
            for (int t = 0; t < 4; t++) p[t] += __shfl_xor(p[t], 1);
            #pragma unroll
            for (int t = 0; t < 4; t++) p[t] += __shfl_xor(p[t], 2);
            #pragma unroll
            for (int t = 0; t < 4; t++) p[t] += __shfl_xor(p[t], 4);
            #pragma unroll
            for (int t = 0; t < 4; t++) {
                // phantom slot (i+t >= end): wave-uniform mask -> ex = 0
                const float ex = (i + t < end) ? __expf(p[t] * csc[t]) : 0.0f;
                den[t] += ex;
                const float e0 = bf2f(ceb[t].x & 0xffffu), e1 = bf2f(ceb[t].x >> 16);
                const float e2 = bf2f(ceb[t].y & 0xffffu), e3 = bf2f(ceb[t].y >> 16);
                ax0[t] = fmaf(bf2f(ckv[t].z & 0xffffu) + e0, ex, ax0[t]);
                ax1[t] = fmaf(bf2f(ckv[t].z >> 16) + e1, ex, ax1[t]);
                ax2[t] = fmaf(bf2f(ckv[t].w & 0xffffu) + e2, ex, ax2[t]);
                ax3[t] = fmaf(bf2f(ckv[t].w >> 16) + e3, ex, ax3[t]);
            }
        }
    }
    const float dn = 1.0f / (den[0] + den[1] + den[2] + den[3] + 1e-16f);
    const float a0 = ax0[0] + ax0[1] + ax0[2] + ax0[3];
    const float a1 = ax1[0] + ax1[1] + ax1[2] + ax1[3];
    const float a2 = ax2[0] + ax2[1] + ax2[2] + ax2[3];
    const float a3 = ax3[0] + ax3[1] + ax3[2] + ax3[3];
    const size_t o = (size_t)n * DIM + lane * 4;
    float4 xr = *(const float4*)(xsrc + o);
    if (lnx_s) {
        float2 t = ln_ms(lnx_s);
        const float4 g4 = *(const float4*)(lnx_g + lane * 4);
        const float4 b4 = *(const float4*)(lnx_b + lane * 4);
        xr = lnaff(xr, g4, b4, t.x, t.y);
    }
    const float4 sr = *(const float4*)(qs + (size_t)n * 512 + 256 + lane * 4);
    float4 out;
    out.x = xr.x + a0 * dn + sr.x;
    out.y = xr.y + a1 * dn + sr.y;
    out.z = xr.z + a2 * dn + sr.z;
    out.w = xr.w + a3 * dn + sr.w;
    *(float4*)(y + o) = out;
    // LN1 stats
    float s1 = out.x + out.y + out.z + out.w;
    float s2 = out.x * out.x + out.y * out.y + out.z * out.z + out.w * out.w;
    #pragma unroll
    for (int of = 32; of > 0; of >>= 1) {
        s1 += __shfl_down(s1, of);
        s2 += __shfl_down(s2, of);
    }
    if (lane == 0) { rs[wv] = s1; rs[4 + wv] = s2; }
    __syncthreads();
    if (threadIdx.x == 0) {
        atomicAdd(&ostats[0], rs[0] + rs[1] + rs[2] + rs[3]);
        atomicAdd(&ostats[1], rs[4] + rs[5] + rs[6] + rs[7]);
    }
}

// ---------------- final LN apply (only for d_out) ----------------
__global__ __launch_bounds__(256) void apply_k(
    const float* __restrict__ y, const float* __restrict__ stats,
    const float* __restrict__ g, const float* __restrict__ b,
    float* __restrict__ xo)
{
    int idx = blockIdx.x * blockDim.x + threadIdx.x;  // float4 index
    float2 t = ln_ms(stats);
    int cb = (idx & 63) * 4;
    float4 v  = *(const float4*)(y + (size_t)idx * 4);
    float4 gv = *(const float4*)(g + cb);
    float4 bv = *(const float4*)(b + cb);
    *(float4*)(xo + (size_t)idx * 4) = lnaff(v, gv, bv, t.x, t.y);
}

extern "C" void kernel_launch(void* const* d_in, const int* in_sizes, int n_in,
                              void* d_out, int out_size, void* d_ws, size_t ws_size,
                              hipStream_t stream) {
    const float* x_in   = (const float*)d_in[0];
    const int*   ei     = (const int*)d_in[1];
    const int*   src    = ei;                 // edge_index[0]
    const int*   dstp   = ei + N_EDGES;       // edge_index[1]
    const float* x_edge = (const float*)d_in[2];
    const float* x_dist = (const float*)d_in[3];
    const float* Wq  = (const float*)d_in[4];
    const float* bq  = (const float*)d_in[5];
    const float* Wk  = (const float*)d_in[6];
    const float* bk  = (const float*)d_in[7];
    const float* Wv  = (const float*)d_in[8];
    const float* bv  = (const float*)d_in[9];
    const float* We  = (const float*)d_in[10];
    const float* Wsk = (const float*)d_in[11];
    const float* bsk = (const float*)d_in[12];
    const float* g1  = (const float*)d_in[13];
    const float* b1  = (const float*)d_in[14];
    const float* W1  = (const float*)d_in[15];
    const float* c1  = (const float*)d_in[16];
    const float* W2  = (const float*)d_in[17];
    const float* c2  = (const float*)d_in[18];
    const float* g2  = (const float*)d_in[19];
    const float* b2  = (const float*)d_in[20];

    // ---- workspace carve ----
    char* p = (char*)d_ws;
    float* ybuf = (float*)p; p += (size_t)N_NODES * DIM * sizeof(float);           // 16.4 MB
    float* qsb  = (float*)p; p += (size_t)N_NODES * 512 * sizeof(float);           // 32.8 MB  [Q|S] fp32
    __hip_bfloat16* kvb = (__hip_bfloat16*)p; p += (size_t)N_NODES * 512 * 2;      // 16.4 MB  [K|V] bf16 interleaved
    __hip_bfloat16* hb16 = (__hip_bfloat16*)p; p += (size_t)N_NODES * 1024 * 2;    // 32.8 MB
    __hip_bfloat16* Ep   = (__hip_bfloat16*)p; p += (size_t)N_EDGES * DIM * 2;     // 131 MB
    __hip_bfloat16* xeb  = (__hip_bfloat16*)p; p += (size_t)N_EDGES * DIM * 2;     // 131 MB
    __hip_bfloat16* WqkvsT = (__hip_bfloat16*)p; p += (size_t)3 * 1024 * 256 * 2;  // [Wq|Wsk|Wk|Wv]^T
    __hip_bfloat16* WeT    = (__hip_bfloat16*)p; p += (size_t)3 * 256 * 256 * 2;
    __hip_bfloat16* W1T    = (__hip_bfloat16*)p; p += (size_t)3 * 1024 * 256 * 2;
    __hip_bfloat16* W2T    = (__hip_bfloat16*)p; p += (size_t)3 * 256 * 1024 * 2;
    float* bqkvs = (float*)p; p += (size_t)3 * 1024 * sizeof(float);               // [bq|bsk|bk|bv]
    float* stats = (float*)p;  p += 64;                       // [block][ln1_s,ln1_ss,ln2_s,ln2_ss]
    int* deg     = (int*)p;    p += (size_t)N_NODES * sizeof(int);
    int* rowptr  = (int*)p;    p += (size_t)(N_NODES + 4) * sizeof(int);
    int* cursor  = (int*)p;    p += (size_t)N_NODES * sizeof(int);
    int* eperm   = (int*)p;    p += (size_t)N_EDGES * sizeof(int);
    int* srcp    = (int*)p;    p += (size_t)N_EDGES * sizeof(int);
    float* scale = (float*)p;  p += (size_t)N_EDGES * sizeof(float);

    const dim3 blk(256);

    // ---- CSR build (edge list constant across blocks) ----
    hipMemsetAsync(deg, 0, (size_t)N_NODES * sizeof(int), stream);
    hipMemsetAsync(stats, 0, 48, stream);
    hist_k<<<N_EDGES / 256, blk, 0, stream>>>(dstp, deg);
    scan_k<<<1, 1024, 0, stream>>>(deg, rowptr, cursor);
    scatter_k<<<N_EDGES / 256, blk, 0, stream>>>(dstp, src, x_dist, cursor, eperm, srcp, scale);
    eprep_k<<<N_EDGES / 4, blk, 0, stream>>>(x_edge, eperm, xeb);

    // ---- weight prep: transpose + bf16 convert, order [Q|S|K|V] ----
    tcvt4_k<<<dim3(8, 8, 12), blk, 0, stream>>>(Wq, Wsk, Wk, Wv, WqkvsT);
    tcvt_k<<<dim3(8, 8, 3), blk, 0, stream>>>(We,  WeT, 256, 256, 65536, 65536);
    tcvt_k<<<dim3(32, 8, 3), blk, 0, stream>>>(W1, W1T, 256, 1024, 262144, 262144);
    tcvt_k<<<dim3(8, 32, 3), blk, 0, stream>>>(W2, W2T, 1024, 256, 262144, 262144);
    bcat_k<<<dim3(4, 3), blk, 0, stream>>>(bq, bsk, bk, bv, bqkvs);

    for (int i = 0; i < 3; i++) {
        const size_t bo = (size_t)i * DIM;
        const size_t b1o = (size_t)i * DFF;
        float* ln1 = stats + (size_t)i * 4;
        float* ln2 = stats + (size_t)i * 4 + 2;
        // LN2 of previous block, applied on-read to x
        const float* pls = (i == 0) ? nullptr : stats + (size_t)(i - 1) * 4 + 2;
        const float* plg = (i == 0) ? nullptr : g2 + (size_t)(i - 1) * 256;
        const float* plb = (i == 0) ? nullptr : b2 + (size_t)(i - 1) * 256;
        const float* xsrc = (i == 0) ? x_in : ybuf;

        // merged: edge projection (4000 blocks) + Q|S|K|V projection (1000 blocks)
        projedge_k<<<5000, blk, 0, stream>>>(
            xsrc, WqkvsT + (size_t)i * 262144, bqkvs + (size_t)i * 1024, qsb, kvb,
            xeb, WeT + (size_t)i * 65536, Ep, pls, plg, plb);
        // attention aggregation + residual + skip + LN1 stats -> ybuf
        node_agg_k<<<N_NODES / 4, blk, 0, stream>>>(qsb, kvb, Ep, srcp, scale, rowptr,
                                                    xsrc, pls, plg, plb, ybuf, ln1);
        // FFN1: LN1(y) x W1 + bias + relu -> bf16
        mgemm_k<1,1,0,1,1,128><<<dim3(8, 125), blk, 0, stream>>>(
            ybuf, W1T + (size_t)i * 262144, c1 + b1o, nullptr,
            hb16, nullptr, N_NODES, DIM, DFF, ln1, g1 + bo, b1 + bo, nullptr, nullptr, nullptr, nullptr);
        // FFN2: h x W2 + bias + LN1(y) residual -> ybuf (in-place) + LN2 stats
        // TM=64: grid (2,250)=500 blocks -> 2 blocks/CU
        mgemm_k<1,0,1,0,0,64><<<dim3(2, 250), blk, 0, stream>>>(
            hb16, W2T + (size_t)i * 262144, c2 + bo, ybuf,
            ybuf, nullptr, N_NODES, DFF, DIM, nullptr, nullptr, nullptr, ln1, g1 + bo, b1 + bo, ln2);
        if (i == 2)
            apply_k<<<(N_NODES * DIM) / 1024, blk, 0, stream>>>(
                ybuf, ln2, g2 + bo, b2 + bo, (float*)d_out);
    }
}